// Round 7
// baseline (228.161 us; speedup 1.0000x reference)
//
#include <hip/hip_runtime.h>
#include <math.h>

// EdgeConv: B=16, N=8192, K=20, D=64 — fused persistent kernel.
// Phase 1 (proj, MFMA): Y1[p][o]=sum_d x[p][d]*W[o][d] (bf16), Bs[p][o]=sum_d x[p][d]*(W[o][64+d]-W[o][d]) (bf16)
// grid barrier (device-scope)
// Phase 2 (gather): out = GELU(LN(max_k Y1[idx_k] + Bs))
// XCD-consistent: block bx -> XCD bx%8 handles batches {2*(bx%8), 2*(bx%8)+1} in BOTH phases,
// so gather reads hit the same XCD's L2 that proj wrote.
#define B_ 16
#define N_ 8192
#define K_ 20
#define NPTS (B_ * N_)   // 131072
#define NBLK 512         // 2 blocks/CU, co-residency guaranteed by __launch_bounds__(256,2)

typedef __attribute__((ext_vector_type(4))) float f4;
typedef __attribute__((ext_vector_type(8))) short s8;           // 8 x bf16 MFMA fragment
typedef __attribute__((ext_vector_type(4))) unsigned int u4;    // 16B untyped
typedef __attribute__((ext_vector_type(4))) unsigned short us4; // 8B packed bf16

__device__ __forceinline__ unsigned short f2bf(float f) {
    union { float f; unsigned u; } v; v.f = f;
    return (unsigned short)((v.u + 0x7FFFu + ((v.u >> 16) & 1u)) >> 16);   // RNE
}
__device__ __forceinline__ float bfhi(unsigned w) { return __uint_as_float(w & 0xFFFF0000u); }
__device__ __forceinline__ float bflo(unsigned w) { return __uint_as_float(w << 16); }

__global__ __launch_bounds__(256, 2) void fused_kernel(
        const float* __restrict__ x, const int* __restrict__ ind,
        const float* __restrict__ W, const float* __restrict__ gamma,
        const float* __restrict__ beta, float* __restrict__ out,
        unsigned short* __restrict__ Y1, unsigned short* __restrict__ Bs,
        unsigned* __restrict__ bar_cnt, unsigned* __restrict__ bar_flag) {
    __shared__ unsigned short Wl[128 * 72];   // row stride 144B; 2-way bank alias = free
    const int t = threadIdx.x;
    const int bx = blockIdx.x;
    const int xcd = bx & 7;            // assumed round-robin block->XCD
    const int lb = bx >> 3;            // 0..63 within XCD
    const int bt = 2 * xcd + (lb >> 5);// batch handled by this block (both phases)
    const int w = lb & 31;             // worker id within batch, 0..31

    // ---- Phase 0: stage combined W (fp32 -> bf16) directly into LDS ----
    for (int i = t; i < 8192; i += 256) {
        const int j = i >> 6, d = i & 63;   // coalesced: 64 lanes read 256B of one W row
        const float v = (j < 64) ? W[j * 128 + d]
                                 : (W[(j - 64) * 128 + 64 + d] - W[(j - 64) * 128 + d]);
        Wl[j * 72 + d] = f2bf(v);
    }
    __syncthreads();

    const int lane = t & 63;
    const int wv = t >> 6;
    const int m = lane & 15;
    const int q = lane >> 4;

    // ---- Phase 1: proj. 4 tiles of 64 points (this batch only) ----
#pragma unroll 1
    for (int tl = 0; tl < 4; ++tl) {
        const int pbase = bt * N_ + (w * 4 + tl) * 64 + wv * 16;

        const float* xr = x + (size_t)(pbase + m) * 64 + q * 8;
        f4 x0 = *(const f4*)(xr);
        f4 x1 = *(const f4*)(xr + 4);
        f4 x2 = *(const f4*)(xr + 32);
        f4 x3 = *(const f4*)(xr + 36);
        s8 X0, X1;
        X0[0]=(short)f2bf(x0.x); X0[1]=(short)f2bf(x0.y); X0[2]=(short)f2bf(x0.z); X0[3]=(short)f2bf(x0.w);
        X0[4]=(short)f2bf(x1.x); X0[5]=(short)f2bf(x1.y); X0[6]=(short)f2bf(x1.z); X0[7]=(short)f2bf(x1.w);
        X1[0]=(short)f2bf(x2.x); X1[1]=(short)f2bf(x2.y); X1[2]=(short)f2bf(x2.z); X1[3]=(short)f2bf(x2.w);
        X1[4]=(short)f2bf(x3.x); X1[5]=(short)f2bf(x3.y); X1[6]=(short)f2bf(x3.z); X1[7]=(short)f2bf(x3.w);

        f4 acc[8];
#pragma unroll
        for (int tt = 0; tt < 8; ++tt) acc[tt] = (f4)0.f;
#pragma unroll
        for (int s = 0; s < 2; ++s) {
            const s8 X = s ? X1 : X0;
#pragma unroll
            for (int tt = 0; tt < 8; ++tt) {
                s8 wf = *(const s8*)((const char*)Wl + (16 * tt + m) * 144 + s * 64 + q * 16);
                acc[tt] = __builtin_amdgcn_mfma_f32_16x16x32_bf16(wf, X, acc[tt], 0, 0, 0);
            }
        }
        // D: o = 16*tt + q*4 + j, point = pbase + m -> packed 8B stores
        const size_t prow = (size_t)(pbase + m) * 64;
#pragma unroll
        for (int tt = 0; tt < 4; ++tt) {
            us4 u;
            u.x = f2bf(acc[tt][0]); u.y = f2bf(acc[tt][1]);
            u.z = f2bf(acc[tt][2]); u.w = f2bf(acc[tt][3]);
            *(us4*)&Y1[prow + tt * 16 + q * 4] = u;
        }
#pragma unroll
        for (int tt = 4; tt < 8; ++tt) {
            us4 u;
            u.x = f2bf(acc[tt][0]); u.y = f2bf(acc[tt][1]);
            u.z = f2bf(acc[tt][2]); u.w = f2bf(acc[tt][3]);
            *(us4*)&Bs[prow + (tt - 4) * 16 + q * 4] = u;
        }
    }

    // ---- Grid barrier (device scope; bar_cnt/bar_flag zeroed by memset node) ----
    __syncthreads();
    if (t == 0) {
        __threadfence();                                // release: wb dirty L2 lines
        unsigned old = atomicAdd(bar_cnt, 1u);
        if (old == (unsigned)(NBLK - 1)) {
            atomicExch(bar_flag, 1u);
        } else {
            long guard = 0;
            while (__hip_atomic_load(bar_flag, __ATOMIC_ACQUIRE, __HIP_MEMORY_SCOPE_AGENT) == 0u) {
                __builtin_amdgcn_s_sleep(4);
                if (++guard > 200000000L) break;        // fail loud (verif) rather than hang
            }
        }
        __threadfence();                                // acquire
    }
    __syncthreads();

    // ---- Phase 2: gather + max + LN + GELU. 256 points (this batch), L2-local Y1 ----
    const int sub = lane & 7;     // channel group (8 ch)
    const int q2 = lane >> 3;     // point within wave
    const int bbase = bt * N_ * 64;
#pragma unroll 1
    for (int it = 0; it < 8; ++it) {
        const int p = bt * N_ + w * 256 + it * 32 + wv * 8 + q2;

        int idxs[K_];
        const int4* ip = (const int4*)&ind[p * K_];   // 80B/point, 16B-aligned
#pragma unroll
        for (int v = 0; v < 5; ++v) {
            int4 iv = ip[v];
            idxs[4 * v + 0] = iv.x; idxs[4 * v + 1] = iv.y;
            idxs[4 * v + 2] = iv.z; idxs[4 * v + 3] = iv.w;
        }

        f4 ma = (f4)(-INFINITY), mb = (f4)(-INFINITY);
#pragma unroll
        for (int r = 0; r < 2; ++r) {     // 2 rounds x 10 outstanding 16B gathers
            u4 rv[10];
#pragma unroll
            for (int k = 0; k < 10; ++k)
                rv[k] = *(const u4*)(Y1 + bbase + idxs[r * 10 + k] * 64 + sub * 8);
#pragma unroll
            for (int k = 0; k < 10; ++k) {
                ma.x = fmaxf(ma.x, bflo(rv[k].x)); ma.y = fmaxf(ma.y, bfhi(rv[k].x));
                ma.z = fmaxf(ma.z, bflo(rv[k].y)); ma.w = fmaxf(ma.w, bfhi(rv[k].y));
                mb.x = fmaxf(mb.x, bflo(rv[k].z)); mb.y = fmaxf(mb.y, bfhi(rv[k].z));
                mb.z = fmaxf(mb.z, bflo(rv[k].w)); mb.w = fmaxf(mb.w, bfhi(rv[k].w));
            }
        }

        u4 bsv = *(const u4*)(Bs + (size_t)p * 64 + sub * 8);
        f4 ha, hb;
        ha.x = ma.x + bflo(bsv.x); ha.y = ma.y + bfhi(bsv.x);
        ha.z = ma.z + bflo(bsv.y); ha.w = ma.w + bfhi(bsv.y);
        hb.x = mb.x + bflo(bsv.z); hb.y = mb.y + bfhi(bsv.z);
        hb.z = mb.z + bflo(bsv.w); hb.w = mb.w + bfhi(bsv.w);

        // LN over 64 ch = 8 comps x 8 lanes (xor 1,2,4 stay within the point's lane group)
        float s = ha.x + ha.y + ha.z + ha.w + hb.x + hb.y + hb.z + hb.w;
#pragma unroll
        for (int off = 4; off >= 1; off >>= 1) s += __shfl_xor(s, off, 64);
        const float mu = s * (1.0f / 64.0f);
        f4 da = ha - mu, db = hb - mu;
        float v2 = da.x * da.x + da.y * da.y + da.z * da.z + da.w * da.w
                 + db.x * db.x + db.y * db.y + db.z * db.z + db.w * db.w;
#pragma unroll
        for (int off = 4; off >= 1; off >>= 1) v2 += __shfl_xor(v2, off, 64);
        const float rstd = rsqrtf(v2 * (1.0f / 64.0f) + 1e-5f);

        const f4 g0 = *(const f4*)&gamma[sub * 8];
        const f4 g1 = *(const f4*)&gamma[sub * 8 + 4];
        const f4 b0 = *(const f4*)&beta[sub * 8];
        const f4 b1 = *(const f4*)&beta[sub * 8 + 4];
        f4 na = da * rstd * g0 + b0;
        f4 nb = db * rstd * g1 + b1;

        f4 r0, r1;
        r0.x = 0.5f * na.x * (1.0f + erff(na.x * 0.70710678f));
        r0.y = 0.5f * na.y * (1.0f + erff(na.y * 0.70710678f));
        r0.z = 0.5f * na.z * (1.0f + erff(na.z * 0.70710678f));
        r0.w = 0.5f * na.w * (1.0f + erff(na.w * 0.70710678f));
        r1.x = 0.5f * nb.x * (1.0f + erff(nb.x * 0.70710678f));
        r1.y = 0.5f * nb.y * (1.0f + erff(nb.y * 0.70710678f));
        r1.z = 0.5f * nb.z * (1.0f + erff(nb.z * 0.70710678f));
        r1.w = 0.5f * nb.w * (1.0f + erff(nb.w * 0.70710678f));
        float* op = &out[(size_t)p * 64 + sub * 8];
        __builtin_nontemporal_store(r0, (f4*)op);
        __builtin_nontemporal_store(r1, (f4*)(op + 4));
    }
}

extern "C" void kernel_launch(void* const* d_in, const int* in_sizes, int n_in,
                              void* d_out, int out_size, void* d_ws, size_t ws_size,
                              hipStream_t stream) {
    const float* x     = (const float*)d_in[0];
    const int*   ind   = (const int*)d_in[1];
    const float* W     = (const float*)d_in[2];
    const float* gamma = (const float*)d_in[3];
    const float* beta  = (const float*)d_in[4];
    float* out = (float*)d_out;

    unsigned short* Bs = (unsigned short*)d_ws;          // 16.8 MB bf16
    unsigned short* Y1 = Bs + (size_t)NPTS * 64;         // 16.8 MB bf16
    unsigned* bar = (unsigned*)((char*)d_ws + (size_t)NPTS * 64 * 4);  // 8B barrier state

    hipMemsetAsync(bar, 0, 8, stream);   // capturable memset node: zero barrier cnt+flag
    fused_kernel<<<NBLK, 256, 0, stream>>>(x, ind, W, gamma, beta, out, Y1, Bs,
                                           bar, bar + 1);
}

// Round 8
// 134.540 us; speedup vs baseline: 1.6959x; 1.6959x over previous
//
#include <hip/hip_runtime.h>
#include <math.h>

// EdgeConv: B=16, N=8192, K=20, D=64 — two-kernel structure (fusion regressed: occupancy loss
// beat L2-locality gain; gather is latency-hiding-bound and needs 8 waves/SIMD).
// Y1[p][o] = sum_d x[p][d]*W[o][d]                (bf16 table, gathered)
// Bs[p][o] = sum_d x[p][d]*(W[o][64+d]-W[o][d])   (bf16, streamed)
// out = GELU(LN(max_k Y1[idx_k] + Bs))
#define B_ 16
#define N_ 8192
#define K_ 20
#define NPTS (B_ * N_)   // 131072

typedef __attribute__((ext_vector_type(4))) float f4;
typedef __attribute__((ext_vector_type(8))) short s8;           // 8 x bf16 MFMA fragment
typedef __attribute__((ext_vector_type(4))) unsigned int u4;    // 16B untyped
typedef __attribute__((ext_vector_type(4))) unsigned short us4; // 8B packed bf16

__device__ __forceinline__ unsigned short f2bf(float f) {
    union { float f; unsigned u; } v; v.f = f;
    return (unsigned short)((v.u + 0x7FFFu + ((v.u >> 16) & 1u)) >> 16);   // RNE
}
__device__ __forceinline__ float bfhi(unsigned w) { return __uint_as_float(w & 0xFFFF0000u); }
__device__ __forceinline__ float bflo(unsigned w) { return __uint_as_float(w << 16); }

// ---------------- Kernel 0: combined W in bf16 (row-major [128][64]) ----------------
// j<64 -> W[j][d] ; j>=64 -> W[j-64][64+d]-W[j-64][d]
__global__ __launch_bounds__(256) void prep_kernel(const float* __restrict__ W,
                                                   unsigned short* __restrict__ Wg) {
    const int i = blockIdx.x * 256 + threadIdx.x;   // 8192 elems
    const int j = i >> 6, d = i & 63;
    const float v = (j < 64) ? W[j * 128 + d]
                             : (W[(j - 64) * 128 + 64 + d] - W[(j - 64) * 128 + d]);
    Wg[i] = f2bf(v);
}

// ---------------- Kernel 1: projections via MFMA (A=W from L1, B=x) ----------------
// No LDS, no barrier: Wg (16 KB) is L1-resident per CU; its row-major layout IS the
// A-fragment layout (lane(m,q) reads 16B at row(16tt+m)*128B + s*64 + q*16, all aligned).
// D-layout: o = 16*tt + q*4 + j, point = pbase + m -> lane stores packed 8B us4.
__global__ __launch_bounds__(256) void proj_kernel(const float* __restrict__ x,
                                                   const unsigned short* __restrict__ Wg,
                                                   unsigned short* __restrict__ Y1,
                                                   unsigned short* __restrict__ Bs) {
    const int t = threadIdx.x;
    const int lane = t & 63;
    const int wv = t >> 6;
    const int m = lane & 15;
    const int q = lane >> 4;
    const int pbase = blockIdx.x * 64 + wv * 16;

    // B-frag (x): lane reads 16B-contig chunks of its point's row, cvt fp32->bf16
    const float* xr = x + (size_t)(pbase + m) * 64 + q * 8;
    f4 x0 = *(const f4*)(xr);
    f4 x1 = *(const f4*)(xr + 4);
    f4 x2 = *(const f4*)(xr + 32);
    f4 x3 = *(const f4*)(xr + 36);
    s8 X0, X1;
    X0[0]=(short)f2bf(x0.x); X0[1]=(short)f2bf(x0.y); X0[2]=(short)f2bf(x0.z); X0[3]=(short)f2bf(x0.w);
    X0[4]=(short)f2bf(x1.x); X0[5]=(short)f2bf(x1.y); X0[6]=(short)f2bf(x1.z); X0[7]=(short)f2bf(x1.w);
    X1[0]=(short)f2bf(x2.x); X1[1]=(short)f2bf(x2.y); X1[2]=(short)f2bf(x2.z); X1[3]=(short)f2bf(x2.w);
    X1[4]=(short)f2bf(x3.x); X1[5]=(short)f2bf(x3.y); X1[6]=(short)f2bf(x3.z); X1[7]=(short)f2bf(x3.w);

    f4 acc[8];
#pragma unroll
    for (int tt = 0; tt < 8; ++tt) acc[tt] = (f4)0.f;

#pragma unroll
    for (int s = 0; s < 2; ++s) {
        const s8 X = s ? X1 : X0;
#pragma unroll
        for (int tt = 0; tt < 8; ++tt) {
            // A-frag straight from global (L1-hot): A[16tt+m][k = s*32 + q*8 + j]
            s8 wf = *(const s8*)(Wg + (16 * tt + m) * 64 + s * 32 + q * 8);
            acc[tt] = __builtin_amdgcn_mfma_f32_16x16x32_bf16(wf, X, acc[tt], 0, 0, 0);
        }
    }

    const size_t prow = (size_t)(pbase + m) * 64;
#pragma unroll
    for (int tt = 0; tt < 4; ++tt) {
        us4 u;
        u.x = f2bf(acc[tt][0]); u.y = f2bf(acc[tt][1]);
        u.z = f2bf(acc[tt][2]); u.w = f2bf(acc[tt][3]);
        *(us4*)&Y1[prow + tt * 16 + q * 4] = u;
    }
#pragma unroll
    for (int tt = 4; tt < 8; ++tt) {
        us4 u;
        u.x = f2bf(acc[tt][0]); u.y = f2bf(acc[tt][1]);
        u.z = f2bf(acc[tt][2]); u.w = f2bf(acc[tt][3]);
        *(us4*)&Bs[prow + (tt - 4) * 16 + q * 4] = u;
    }
}

// ---------------- Kernel 2: gather + max + LN + GELU ----------------
// 8 points/wave, 8 lanes/point, 8 ch/lane: 16B gathers. High occupancy (VGPR~36,
// 8 waves/SIMD) hides the idx->gather latency chain.
// XCD-pinned: batch bt = blockIdx&15 -> XCD bt%8 caches 2 batches (2.1MB bf16 table).
__global__ __launch_bounds__(256) void gather_kernel(const unsigned short* __restrict__ Y1,
                                                     const unsigned short* __restrict__ Bs,
                                                     const int* __restrict__ ind,
                                                     const float* __restrict__ gamma,
                                                     const float* __restrict__ beta,
                                                     float* __restrict__ out) {
    const int lane = threadIdx.x & 63;
    const int wave = threadIdx.x >> 6;
    const int sub = lane & 7;            // channel group (8 ch)
    const int q = lane >> 3;             // point within wave
    const int bi = blockIdx.x;           // 4096 blocks
    const int bt = bi & 15;
    const int jj = bi >> 4;
    const int p = bt * N_ + jj * 32 + wave * 8 + q;
    const int bbase = bt * N_ * 64;

    int idxs[K_];
    const int4* ip = (const int4*)&ind[p * K_];   // 80B/point, 16B-aligned
#pragma unroll
    for (int v = 0; v < 5; ++v) {
        int4 iv = ip[v];
        idxs[4 * v + 0] = iv.x; idxs[4 * v + 1] = iv.y;
        idxs[4 * v + 2] = iv.z; idxs[4 * v + 3] = iv.w;
    }

    f4 ma = (f4)(-INFINITY), mb = (f4)(-INFINITY);
#pragma unroll
    for (int r = 0; r < 2; ++r) {        // 2 rounds x 10 outstanding 16B gathers
        u4 rv[10];
#pragma unroll
        for (int k = 0; k < 10; ++k)
            rv[k] = *(const u4*)(Y1 + bbase + idxs[r * 10 + k] * 64 + sub * 8);
#pragma unroll
        for (int k = 0; k < 10; ++k) {
            ma.x = fmaxf(ma.x, bflo(rv[k].x)); ma.y = fmaxf(ma.y, bfhi(rv[k].x));
            ma.z = fmaxf(ma.z, bflo(rv[k].y)); ma.w = fmaxf(ma.w, bfhi(rv[k].y));
            mb.x = fmaxf(mb.x, bflo(rv[k].z)); mb.y = fmaxf(mb.y, bfhi(rv[k].z));
            mb.z = fmaxf(mb.z, bflo(rv[k].w)); mb.w = fmaxf(mb.w, bfhi(rv[k].w));
        }
    }

    u4 bsv = __builtin_nontemporal_load((const u4*)(Bs + (size_t)p * 64 + sub * 8));
    f4 ha, hb;
    ha.x = ma.x + bflo(bsv.x); ha.y = ma.y + bfhi(bsv.x);
    ha.z = ma.z + bflo(bsv.y); ha.w = ma.w + bfhi(bsv.y);
    hb.x = mb.x + bflo(bsv.z); hb.y = mb.y + bfhi(bsv.z);
    hb.z = mb.z + bflo(bsv.w); hb.w = mb.w + bfhi(bsv.w);

    // LN over 64 ch = 8 comps x 8 lanes (xor 1,2,4 stay within the point's lane group)
    float s = ha.x + ha.y + ha.z + ha.w + hb.x + hb.y + hb.z + hb.w;
#pragma unroll
    for (int off = 4; off >= 1; off >>= 1) s += __shfl_xor(s, off, 64);
    const float mu = s * (1.0f / 64.0f);
    f4 da = ha - mu, db = hb - mu;
    float v2 = da.x * da.x + da.y * da.y + da.z * da.z + da.w * da.w
             + db.x * db.x + db.y * db.y + db.z * db.z + db.w * db.w;
#pragma unroll
    for (int off = 4; off >= 1; off >>= 1) v2 += __shfl_xor(v2, off, 64);
    const float rstd = rsqrtf(v2 * (1.0f / 64.0f) + 1e-5f);

    const f4 g0 = *(const f4*)&gamma[sub * 8];
    const f4 g1 = *(const f4*)&gamma[sub * 8 + 4];
    const f4 b0 = *(const f4*)&beta[sub * 8];
    const f4 b1 = *(const f4*)&beta[sub * 8 + 4];
    f4 na = da * rstd * g0 + b0;
    f4 nb = db * rstd * g1 + b1;

    f4 r0, r1;
    r0.x = 0.5f * na.x * (1.0f + erff(na.x * 0.70710678f));
    r0.y = 0.5f * na.y * (1.0f + erff(na.y * 0.70710678f));
    r0.z = 0.5f * na.z * (1.0f + erff(na.z * 0.70710678f));
    r0.w = 0.5f * na.w * (1.0f + erff(na.w * 0.70710678f));
    r1.x = 0.5f * nb.x * (1.0f + erff(nb.x * 0.70710678f));
    r1.y = 0.5f * nb.y * (1.0f + erff(nb.y * 0.70710678f));
    r1.z = 0.5f * nb.z * (1.0f + erff(nb.z * 0.70710678f));
    r1.w = 0.5f * nb.w * (1.0f + erff(nb.w * 0.70710678f));
    float* op = &out[(size_t)p * 64 + sub * 8];
    __builtin_nontemporal_store(r0, (f4*)op);
    __builtin_nontemporal_store(r1, (f4*)(op + 4));
}

extern "C" void kernel_launch(void* const* d_in, const int* in_sizes, int n_in,
                              void* d_out, int out_size, void* d_ws, size_t ws_size,
                              hipStream_t stream) {
    const float* x     = (const float*)d_in[0];
    const int*   ind   = (const int*)d_in[1];
    const float* W     = (const float*)d_in[2];
    const float* gamma = (const float*)d_in[3];
    const float* beta  = (const float*)d_in[4];
    float* out = (float*)d_out;

    unsigned short* Bs = (unsigned short*)d_ws;          // 16.8 MB bf16
    unsigned short* Y1 = Bs + (size_t)NPTS * 64;         // 16.8 MB bf16
    unsigned short* Wg = Y1 + (size_t)NPTS * 64;         // 16 KB bf16

    prep_kernel<<<32, 256, 0, stream>>>(W, Wg);
    proj_kernel<<<NPTS / 64, 256, 0, stream>>>(x, Wg, Y1, Bs);
    gather_kernel<<<NPTS / 32, 256, 0, stream>>>(Y1, Bs, ind, gamma, beta, out);
}